// Round 1
// baseline (140.152 us; speedup 1.0000x reference)
//
#include <hip/hip_runtime.h>
#include <hip/hip_bf16.h>
#include <stdint.h>

#define WW    361    // W*W spatial positions
#define CCH   64     // channels (K)
#define MH    192    // support rows per job (i-half)
#define NP    368    // query rows padded to 23 tiles of 16
#define NT    23     // NP/16 query tiles
#define NJOBS 1200   // B*S*2 halves
#define NTHR  768    // 12 waves: 1 i-tile per wave
#define GRID  256    // persistent: 1 block/CU, jobs b, b+256, ...

typedef __attribute__((ext_vector_type(8))) short short8;
typedef __attribute__((ext_vector_type(4))) float f32x4;

// LDS layout per buffer: row-major [row][k], pitch 64 bf16 (128B), 16B-chunk
// XOR swizzle: element (m,k) at m*64 + ((k/8 ^ (m&7))*8) + (k&7). Proven
// bank-uniform for both b128 stores and b128 fragment reads (R1/R2).
//
// NEW (this round): persistent blocks, double-buffered jobs. While computing
// job t from buffer cur, each staging thread loads/converts/writes its
// next-job row into buffer cur^1, interleaved into the pt-loop (chunk c
// issued at iter 2c, converted at 2c+3). One barrier per job boundary.

__global__ __launch_bounds__(NTHR, 3) void cossim_max_kernel(
    const float* __restrict__ support, const float* __restrict__ query,
    float* __restrict__ out)
{
  __shared__ __align__(16) unsigned short S_sh[2][MH * CCH];  // 2 x 24576 B
  __shared__ __align__(16) unsigned short Q_sh[2][NP * CCH];  // 2 x 47104 B
  __shared__ float inv_s[2][MH];
  __shared__ float inv_q[2][NP];                              // total 147840 B

  const int tid   = threadIdx.x;
  const int b     = blockIdx.x;
  const int half  = b & 1;            // constant per block (jobs step by 256)
  const int mBase = half * MH;

  // ---- per-thread staging role (job-invariant) ----
  const bool isQ = (tid < NP);
  const bool isS = (tid >= NP) && (tid < NP + MH);
  const int  mRow = isQ ? tid : (tid - NP);            // local row in buffer
  const int  gRow = isQ ? tid : (mBase + (tid - NP));  // global spatial idx
  const bool active_row = (isQ || isS) && (gRow < WW);
  const bool pad_row    = (isQ || isS) && !active_row;
  const int  rsw = mRow & 7;

  // scalar (non-array) buffer pointers: avoid runtime-indexed arrays (scratch)
  unsigned short* dRowA = &Q_sh[0][0];
  unsigned short* dRowB = &Q_sh[1][0];
  float* dInvA = &inv_q[0][0];
  float* dInvB = &inv_q[1][0];
  if (isQ)      { dRowA = &Q_sh[0][mRow*CCH]; dRowB = &Q_sh[1][mRow*CCH];
                  dInvA = &inv_q[0][mRow];    dInvB = &inv_q[1][mRow]; }
  else if (isS) { dRowA = &S_sh[0][mRow*CCH]; dRowB = &S_sh[1][mRow*CCH];
                  dInvA = &inv_s[0][mRow];    dInvB = &inv_s[1][mRow]; }

  const size_t bs0 = (size_t)(b >> 1);
  const size_t jobstride = (size_t)128 * WW * CCH;   // bs advances 128/job
  const float* g = (isQ ? query : support) + bs0 * (size_t)(WW * CCH) + gRow;

  // ---- prologue: stage job 0 into buffer A, 4-deep pipelined ----
  if (active_row) {
    float v[4][8];
    float ss = 0.f;
    #pragma unroll
    for (int c = 0; c < 4; ++c)
      #pragma unroll
      for (int j = 0; j < 8; ++j) v[c][j] = g[(c*8 + j) * WW];
    #pragma unroll
    for (int c = 0; c < 8; ++c) {
      unsigned int u[4];
      float a0 = 0.f, a1 = 0.f;
      #pragma unroll
      for (int jj = 0; jj < 4; ++jj) {
        float x = v[c & 3][2*jj], y = v[c & 3][2*jj + 1];
        a0 += x * x; a1 += y * y;
        __hip_bfloat162 b2 = __float22bfloat162_rn(make_float2(x, y));
        u[jj] = *(unsigned int*)&b2;
      }
      ss += a0 + a1;
      *(uint4*)&dRowA[((c ^ rsw) * 8)] = make_uint4(u[0], u[1], u[2], u[3]);
      if (c < 4) {
        #pragma unroll
        for (int j = 0; j < 8; ++j) v[c][j] = g[((c + 4)*8 + j) * WW];
      }
    }
    dInvA[0] = rsqrtf(ss);
  } else if (pad_row) {
    // pad rows: zero ONCE in both buffers (never rewritten), inv = 0
    #pragma unroll
    for (int c = 0; c < 8; ++c) {
      *(uint4*)&dRowA[c * 8] = make_uint4(0u, 0u, 0u, 0u);
      *(uint4*)&dRowB[c * 8] = make_uint4(0u, 0u, 0u, 0u);
    }
    dInvA[0] = 0.f; dInvB[0] = 0.f;
  }
  __syncthreads();

  // ---- compute-side constants ----
  const int lane = tid & 63;
  const int wv   = tid >> 6;      // 0..11 -> i-tile
  const int l15  = lane & 15;
  const int quad = lane >> 4;
  const int bsw  = l15 & 7;       // == n&7 for every tile (16*pt ≡ 0 mod 8)
  const float lastbias = (l15 < 9) ? 0.f : -1e30f;  // pt=22: n = 352+l15
  const int am    = 16 * wv + l15;
  const int aoff0 = am * CCH + (((0 + quad) ^ (am & 7)) * 8);
  const int aoff1 = am * CCH + (((4 + quad) ^ (am & 7)) * 8);
  const int boff0 = l15 * CCH + (((0 + quad) ^ bsw) * 8);
  const int boff1 = l15 * CCH + (((4 + quad) ^ bsw) * 8);

  int job = b;
  int t = 0;
  size_t outb = bs0 * WW;

  for (;;) {
    const int  cur = t & 1;
    const bool have_next = (job + GRID) < NJOBS;
    const float* gnext = g + jobstride;

    const unsigned short* Sc = cur ? &S_sh[1][0] : &S_sh[0][0];
    const unsigned short* Qc = cur ? &Q_sh[1][0] : &Q_sh[0][0];
    const float*         iqc = cur ? &inv_q[1][0] : &inv_q[0][0];
    unsigned short* dN = cur ? dRowA : dRowB;   // next-job staging targets
    float*          iN = cur ? dInvA : dInvB;

    // A fragments for this job
    short8 af0 = *(const short8*)&Sc[aoff0];
    short8 af1 = *(const short8*)&Sc[aoff1];

    // B-fragment preload for pt=0
    short8 bb0[2], bb1[2];
    float  qv[2];
    bb0[0] = *(const short8*)&Qc[boff0];
    bb1[0] = *(const short8*)&Qc[boff1];
    qv[0]  = iqc[l15];

    f32x4 mx = {-3e38f, -3e38f, -3e38f, -3e38f};
    float ssn = 0.f;
    float fa[2][8];                       // 2 staging chunks in flight
    const bool st = have_next && active_row;

    #pragma unroll
    for (int pt = 0; pt < NT; ++pt) {
      const int pb = pt & 1;
      // prefetch next tile's B fragments + inv_q
      if (pt + 1 < NT) {
        const int nb = 16 * (pt + 1) * CCH;
        bb0[pb ^ 1] = *(const short8*)&Qc[nb + boff0];
        bb1[pb ^ 1] = *(const short8*)&Qc[nb + boff1];
        qv[pb ^ 1]  = iqc[16 * (pt + 1) + l15];
      }
      // interleaved next-job staging: issue chunk c at pt=2c, convert at 2c+3
      if (st) {
        if ((pt & 1) == 0 && pt <= 14) {
          const int c = pt >> 1;
          #pragma unroll
          for (int j = 0; j < 8; ++j) fa[c & 1][j] = gnext[(c*8 + j) * WW];
        } else if ((pt & 1) == 1 && pt >= 3 && pt <= 17) {
          const int c = (pt - 3) >> 1;
          unsigned int u[4];
          float a0 = 0.f, a1 = 0.f;
          #pragma unroll
          for (int jj = 0; jj < 4; ++jj) {
            float x = fa[c & 1][2*jj], y = fa[c & 1][2*jj + 1];
            a0 += x * x; a1 += y * y;
            __hip_bfloat162 b2 = __float22bfloat162_rn(make_float2(x, y));
            u[jj] = *(unsigned int*)&b2;
          }
          ssn += a0 + a1;
          *(uint4*)&dN[((c ^ rsw) * 8)] = make_uint4(u[0], u[1], u[2], u[3]);
        } else if (pt == 19) {
          iN[0] = rsqrtf(ssn);
        }
      }
      // MFMA + max update (no bias needed until the last tile: n<=351<361)
      f32x4 acc = {0.f, 0.f, 0.f, 0.f};
      acc = __builtin_amdgcn_mfma_f32_16x16x32_bf16(af0, bb0[pb], acc, 0, 0, 0);
      acc = __builtin_amdgcn_mfma_f32_16x16x32_bf16(af1, bb1[pb], acc, 0, 0, 0);
      const float qs = qv[pb];
      if (pt < NT - 1) {
        #pragma unroll
        for (int r = 0; r < 4; ++r) mx[r] = fmaxf(mx[r], acc[r] * qs);
      } else {
        #pragma unroll
        for (int r = 0; r < 4; ++r) mx[r] = fmaxf(mx[r], acc[r] * qs + lastbias);
      }
    }

    // max over columns (C layout: col = lane&15): butterfly in 16-lane group
    #pragma unroll
    for (int d = 1; d < 16; d <<= 1) {
      #pragma unroll
      for (int r = 0; r < 4; ++r) mx[r] = fmaxf(mx[r], __shfl_xor(mx[r], d));
    }
    // C/D layout: row = quad*4 + reg; one writer lane per 16-lane group
    if (l15 == 0) {
      const float* isc = cur ? &inv_s[1][0] : &inv_s[0][0];
      #pragma unroll
      for (int r = 0; r < 4; ++r) {
        const int mL = 16 * wv + 4 * quad + r;
        const int iG = mBase + mL;
        if (iG < WW) out[outb + iG] = mx[r] * isc[mL];
      }
    }

    if (!have_next) break;
    __syncthreads();            // staged buffer cur^1 now visible to all
    g = gnext;
    job += GRID;
    ++t;
    outb += (size_t)128 * WW;
  }
}

extern "C" void kernel_launch(void* const* d_in, const int* in_sizes, int n_in,
                              void* d_out, int out_size, void* d_ws, size_t ws_size,
                              hipStream_t stream) {
  const float* support = (const float*)d_in[0];
  const float* query   = (const float*)d_in[1];
  float* out = (float*)d_out;
  dim3 grid(GRID), block(NTHR);
  hipLaunchKernelGGL(cossim_max_kernel, grid, block, 0, stream,
                     support, query, out);
}